// Round 7
// baseline (555.627 us; speedup 1.0000x reference)
//
#include <hip/hip_runtime.h>
#include <hip/hip_bf16.h>

// MultiScaleFeatureExtractor on MI355X (gfx950) — Round 7
// Math restructuring (unchanged):
//   logits = x @ (Wx@Wslice) + (bx@Wslice + bslice)      (px never materialized)
//   out[s,d] = (sum_n w[n,s]*fx[n,d]) / (sum_n w[n,s] + 0.01)
// R7 vs R6 (counter-driven):
//   - R6 falsified the weight-reload theory (AGPR pin changed nothing ->
//     compiler already AGPR-homed weights in R4; trace VGPR_Count excludes
//     accum bank). R5's 307us was "+v" forcing weights into the ARCH pool.
//   - Therefore: fp32-direct A-path is viable WITH "+a" weights (~110 free
//     arch VGPRs). xprep (64us) + 67MB xf DELETED; main converts in-register.
//     x re-read 8x/tile is L2-served: swizzle puts a tile's 8 head-blocks on
//     one XCD (bidx&7 const per tile), tile slice 512KB << 4MB L2.
//   - softmax folded to 2 VALU/elem: e = exp2(fma(acc, kE, bcE)) with
//     kE = invt*log2e, bcE = bc*kE precomputed in prep (temp is a prep input).
//   - ws: 67.9MB -> 0.8MB (harness re-poisons ws each timed call; smaller ws
//     = less poison traffic inside the timed region).
//
// ws layout (NEED = 794,624 B):
//   [0,      524288) WtF  bf16 B-frags [proj(2)][head(8)][nt(4)][ks(8)][lane(64)][j(8)]
//   [524288, 526336) bcE  f32 [512]   (logit bias * kE, exp2-domain)
//   [526336, 528384) kE   f32 [8] (+pad)
//   [528384, 790528) Tg   f32 [B*8*64*64]
//   [790528, 794624) ng   f32 [B*8*64]

typedef __attribute__((ext_vector_type(8))) short short8;
typedef __attribute__((ext_vector_type(4))) float float4v;
typedef __attribute__((ext_vector_type(2))) unsigned int uint2v;

#define MP 36        // wT/fT pitch: 32-token rows + 4 pad shorts (R4/R6 measured 0 conflicts)

__device__ __forceinline__ unsigned short f2bf(float f) {
    union { float f; unsigned int u; } v; v.f = f;
    unsigned int r = (v.u + 0x7FFFu + ((v.u >> 16) & 1u)) >> 16;  // RNE
    return (unsigned short)r;
}

__device__ __forceinline__ unsigned int pack2(float a, float b) {
    __hip_bfloat162 h = __float22bfloat162_rn(float2{a, b});
    union { __hip_bfloat162 h; unsigned int u; } cv; cv.h = h;
    return cv.u;   // low 16 = a, high 16 = b
}

// ---- prep5: fold Wx@Wslice + reformat Wfx into B-frag order; compute bcE/kE.
// grid 321 x 256 (proj0 fold / proj1 reformat verified in R6; b==320 reworked).
__global__ __launch_bounds__(256)
void msfe_prep5(const float* __restrict__ Wx, const float* __restrict__ bx,
                const float* __restrict__ Wfx,
                const float* __restrict__ Wslice, const float* __restrict__ bslice,
                const float* __restrict__ temperature,
                unsigned short* __restrict__ WtF, float* __restrict__ bcE,
                float* __restrict__ kE) {
    const int b = blockIdx.x, t = threadIdx.x;
    if (b < 256) {
        const int head = b >> 5, oct = b & 31;
        __shared__ float Wsl[64 * 65];          // [d][s] +1 pad
        __shared__ float WxS[8 * 64];           // [j][d]
        __shared__ unsigned short stg[8 * 64];  // [j][s]
        #pragma unroll
        for (int i = 0; i < 16; ++i) {          // Wslice: 4096 floats, coalesced
            int idx = i * 256 + t; int d = idx >> 6, s = idx & 63;
            Wsl[d * 65 + s] = Wslice[idx];
        }
        #pragma unroll
        for (int i = 0; i < 2; ++i) {           // 8 Wx rows x 64 ch, coalesced
            int idx = i * 256 + t; int j = idx >> 6, d = idx & 63;
            WxS[j * 64 + d] = Wx[(long)(oct * 8 + j) * 512 + head * 64 + d];
        }
        __syncthreads();
        const int s = t & 63;
        #pragma unroll
        for (int rep = 0; rep < 2; ++rep) {
            int j = (t >> 6) + rep * 4;         // wave-uniform j
            float a0 = 0.f, a1 = 0.f, a2 = 0.f, a3 = 0.f;
            #pragma unroll
            for (int d = 0; d < 64; d += 4) {
                a0 += WxS[j * 64 + d]     * Wsl[(d)     * 65 + s];
                a1 += WxS[j * 64 + d + 1] * Wsl[(d + 1) * 65 + s];
                a2 += WxS[j * 64 + d + 2] * Wsl[(d + 2) * 65 + s];
                a3 += WxS[j * 64 + d + 3] * Wsl[(d + 3) * 65 + s];
            }
            stg[j * 64 + s] = f2bf((a0 + a1) + (a2 + a3));
        }
        __syncthreads();
        if (t < 64) {
            int nt = t >> 4, l16 = t & 15;
            int ks = oct >> 2, quad = oct & 3;
            int lane = quad * 16 + l16;
            short8 o;
            #pragma unroll
            for (int j = 0; j < 8; ++j) o[j] = (short)stg[j * 64 + nt * 16 + l16];
            *(short8*)(WtF + ((((long)(0 * 8 + head) * 4 + nt) * 8 + ks) * 64 + lane) * 8) = o;
        }
    } else if (b < 320) {
        const int head = (b - 256) >> 3, ks = (b - 256) & 7;
        const int nt = t >> 6, lane = t & 63;
        const int quad = lane >> 4, l16 = lane & 15;
        short8 o;
        #pragma unroll
        for (int j = 0; j < 8; ++j)
            o[j] = (short)f2bf(Wfx[(long)(ks * 32 + quad * 8 + j) * 512 + head * 64 + nt * 16 + l16]);
        *(short8*)(WtF + ((((long)(1 * 8 + head) * 4 + nt) * 8 + ks) * 64 + lane) * 8) = o;
    } else {
        const float L2E = 1.4426950408889634f;
        if (t < 8) {
            float tv = fminf(fmaxf(temperature[t], 0.5f), 5.0f);
            kE[t] = L2E / tv;
        }
        #pragma unroll
        for (int p = 0; p < 2; ++p) {
            int j = t + p * 256;
            int h = j >> 6, s = j & 63;
            float bsum = bslice[s];
            for (int d = 0; d < 64; ++d) bsum += bx[h * 64 + d] * Wslice[d * 64 + s];
            float tv = fminf(fmaxf(temperature[h], 0.5f), 5.0f);
            bcE[j] = bsum * (L2E / tv);
        }
    }
}

// ---- main6: 2048 blocks x 256 thr (4 waves), 512-token tiles, 16 x 32-token chunks.
// Weights in AGPRs ("+a"); A-frags converted from fp32 x in-register.
__global__ __launch_bounds__(256, 2)
void msfe_main6(const float* __restrict__ x,
                const unsigned short* __restrict__ WtF,
                const float* __restrict__ bcE,
                const float* __restrict__ bfx,
                const float* __restrict__ kE,
                float* __restrict__ Tg, float* __restrict__ ng) {
    __shared__ unsigned short wT[2][64 * MP];   // [s][token] bf16, double-buffered
    __shared__ unsigned short fT[2][64 * MP];   // [d][token]

    const int tid  = threadIdx.x;
    const int lane = tid & 63;
    const int wv   = tid >> 6;    // 0..3
    const int quad = lane >> 4;
    const int l16  = lane & 15;

    // swizzle: a tile's 8 head-blocks share bidx&7 -> same XCD round -> the
    // tile's 512KB x-slice is L2-resident for the 7 followers.
    const int bidx = blockIdx.x;                     // 0..2047
    const int tile = (bidx >> 6) * 8 + (bidx & 7);   // 0..255 (512 tokens each)
    const int head = (bidx >> 3) & 7;
    const int batch = tile >> 7;

    const int proj = wv >> 1;   // waves 0,1: logits+softmax; 2,3: fx
    const int tw   = wv & 1;    // 16-token sub-tile within 32-token chunk

    // ---- weight fragments -> AGPRs (R6-verified allocation behavior)
    short8 wfr[4][8];
    {
        const unsigned short* wb = WtF + (((long)(proj * 8 + head) * 4) * 8) * 512 + (long)lane * 8;
        #pragma unroll
        for (int nt = 0; nt < 4; ++nt)
            #pragma unroll
            for (int ks = 0; ks < 8; ++ks)
                wfr[nt][ks] = *(const short8*)(wb + (nt * 8 + ks) * 512);
    }
    #pragma unroll
    for (int nt = 0; nt < 4; ++nt)
        #pragma unroll
        for (int ks = 0; ks < 8; ++ks)
            asm volatile("" : "+a"(wfr[nt][ks]));

    float bias[4];
    #pragma unroll
    for (int nt = 0; nt < 4; ++nt)
        bias[nt] = (proj == 0 ? bcE : bfx)[head * 64 + nt * 16 + l16];
    const float kEh = kE[head];

    float4v Tac[4];
    #pragma unroll
    for (int nt = 0; nt < 4; ++nt) Tac[nt] = (float4v){0.f, 0.f, 0.f, 0.f};
    float normAcc[4] = {0.f, 0.f, 0.f, 0.f};

    // A-frags direct from fp32 x: lane(quad,l16) reads token row l16,
    // 8 ch at ks*32+quad*8; per instr the wave covers 16 full 128B segments.
    const float* xrow = x + ((long)tile * 512 + tw * 16 + l16) * 256;
    short8 afr[8];
    #pragma unroll
    for (int ks = 0; ks < 8; ++ks) {
        const float4v* p = (const float4v*)(xrow + ks * 32 + quad * 8);
        float4v v0 = p[0], v1 = p[1];
        union { short8 s; unsigned int u[4]; } cu;
        cu.u[0] = pack2(v0.x, v0.y); cu.u[1] = pack2(v0.z, v0.w);
        cu.u[2] = pack2(v1.x, v1.y); cu.u[3] = pack2(v1.z, v1.w);
        afr[ks] = cu.s;
    }

    for (int c = 0; c < 16; ++c) {
        const int wbuf = c & 1, rbuf = wbuf ^ 1;

        // P1: [16 tok x 64 cols] += A(x) * B(w-AGPRs), K=256
        float4v acc[4];
        #pragma unroll
        for (int nt = 0; nt < 4; ++nt) acc[nt] = (float4v){0.f, 0.f, 0.f, 0.f};
        #pragma unroll
        for (int ks = 0; ks < 8; ++ks) {
            #pragma unroll
            for (int nt = 0; nt < 4; ++nt)
                acc[nt] = __builtin_amdgcn_mfma_f32_16x16x32_bf16(afr[ks], wfr[nt][ks], acc[nt], 0, 0, 0);
        }

        // prefetch+convert next chunk's A-frags (hidden behind P3+P2+barrier;
        // viable now: ~110 arch VGPRs free with weights in the accum bank)
        if (c < 15) {
            #pragma unroll
            for (int ks = 0; ks < 8; ++ks) {
                const float4v* p = (const float4v*)(xrow + (long)(c + 1) * 8192 + ks * 32 + quad * 8);
                float4v v0 = p[0], v1 = p[1];
                union { short8 s; unsigned int u[4]; } cu;
                cu.u[0] = pack2(v0.x, v0.y); cu.u[1] = pack2(v0.z, v0.w);
                cu.u[2] = pack2(v1.x, v1.y); cu.u[3] = pack2(v1.z, v1.w);
                afr[ks] = cu.s;
            }
        }

        // P3 (skewed): T[s][d] += w^T fx over PREVIOUS chunk's 32 tokens.
        if (c > 0) {
            short8 a = *(const short8*)(&wT[rbuf][(wv * 16 + l16) * MP + quad * 8]);
            #pragma unroll
            for (int nt = 0; nt < 4; ++nt) {
                short8 bf = *(const short8*)(&fT[rbuf][(nt * 16 + l16) * MP + quad * 8]);
                Tac[nt] = __builtin_amdgcn_mfma_f32_16x16x32_bf16(a, bf, Tac[nt], 0, 0, 0);
            }
        }

        // P2: softmax / bias -> transposed bf16 into wbuf.
        // C layout: col=l16+16*nt, row=quad*4+rr -> token = tw*16+quad*4+rr
        if (proj == 0) {
            float e[4][4];
            #pragma unroll
            for (int nt = 0; nt < 4; ++nt)
                #pragma unroll
                for (int rr = 0; rr < 4; ++rr)
                    e[nt][rr] = exp2f(fmaf(acc[nt][rr], kEh, bias[nt]));  // 2 VALU/elem
            #pragma unroll
            for (int rr = 0; rr < 4; ++rr) {
                float s = e[0][rr] + e[1][rr] + e[2][rr] + e[3][rr];
                s += __shfl_xor(s, 1); s += __shfl_xor(s, 2);
                s += __shfl_xor(s, 4); s += __shfl_xor(s, 8);
                float inv = 1.0f / s;
                e[0][rr] *= inv; e[1][rr] *= inv; e[2][rr] *= inv; e[3][rr] *= inv;
            }
            #pragma unroll
            for (int nt = 0; nt < 4; ++nt) {
                normAcc[nt] += e[nt][0] + e[nt][1] + e[nt][2] + e[nt][3];
                uint2v p;
                p.x = pack2(e[nt][0], e[nt][1]);
                p.y = pack2(e[nt][2], e[nt][3]);
                *(uint2v*)(&wT[wbuf][(nt * 16 + l16) * MP + tw * 16 + quad * 4]) = p;
            }
        } else {
            #pragma unroll
            for (int nt = 0; nt < 4; ++nt) {
                uint2v p;
                p.x = pack2(acc[nt][0] + bias[nt], acc[nt][1] + bias[nt]);
                p.y = pack2(acc[nt][2] + bias[nt], acc[nt][3] + bias[nt]);
                *(uint2v*)(&fT[wbuf][(nt * 16 + l16) * MP + tw * 16 + quad * 4]) = p;
            }
        }

        __syncthreads();   // single barrier per chunk
    }

    // final P3 on the last written buffer (chunk 15 -> buf 1)
    {
        short8 a = *(const short8*)(&wT[1][(wv * 16 + l16) * MP + quad * 8]);
        #pragma unroll
        for (int nt = 0; nt < 4; ++nt) {
            short8 bf = *(const short8*)(&fT[1][(nt * 16 + l16) * MP + quad * 8]);
            Tac[nt] = __builtin_amdgcn_mfma_f32_16x16x32_bf16(a, bf, Tac[nt], 0, 0, 0);
        }
    }

    // epilogue: atomics into global accumulators
    const int basehs = (batch * 8 + head) * 64;
    #pragma unroll
    for (int nt = 0; nt < 4; ++nt) {
        #pragma unroll
        for (int rr = 0; rr < 4; ++rr) {
            int s = wv * 16 + quad * 4 + rr;
            int d = nt * 16 + l16;
            atomicAdd(&Tg[(basehs + s) * 64 + d], Tac[nt][rr]);
        }
    }
    if (proj == 0) {
        #pragma unroll
        for (int nt = 0; nt < 4; ++nt) {
            float v = normAcc[nt];
            v += __shfl_xor(v, 16);
            v += __shfl_xor(v, 32);
            if (quad == 0) atomicAdd(&ng[basehs + nt * 16 + l16], v);
        }
    }
}

// ---------------- finalize ----------------
__global__ void msfe_final(const float* __restrict__ Tg, const float* __restrict__ ng,
                           float* __restrict__ out) {
    int i = blockIdx.x * 256 + threadIdx.x;
    out[i] = Tg[i] / (ng[i >> 6] + 0.01f);
}

extern "C" void kernel_launch(void* const* d_in, const int* in_sizes, int n_in,
                              void* d_out, int out_size, void* d_ws, size_t ws_size,
                              hipStream_t stream) {
    const float* x       = (const float*)d_in[0];
    const float* Wx      = (const float*)d_in[1];
    const float* bx      = (const float*)d_in[2];
    const float* Wfx     = (const float*)d_in[3];
    const float* bfx     = (const float*)d_in[4];
    const float* Wslice  = (const float*)d_in[5];
    const float* bslice  = (const float*)d_in[6];
    const float* temp    = (const float*)d_in[7];

    char* ws = (char*)d_ws;
    unsigned short* WtF = (unsigned short*)ws;      // 524,288 B
    float* bcE = (float*)(ws + 524288);             //   2,048 B
    float* kE  = (float*)(ws + 526336);             //   2,048 B (8 used)
    float* Tg  = (float*)(ws + 528384);             // 262,144 B
    float* ng  = (float*)(ws + 790528);             //   4,096 B

    hipMemsetAsync(Tg, 0, 262144 + 4096, stream);   // ws re-poisoned 0xAA each call
    msfe_prep5<<<321, 256, 0, stream>>>(Wx, bx, Wfx, Wslice, bslice, temp, WtF, bcE, kE);
    msfe_main6<<<2048, 256, 0, stream>>>(x, WtF, bcE, bfx, kE, Tg, ng);
    msfe_final<<<256, 256, 0, stream>>>(Tg, ng, (float*)d_out);
}